// Round 6
// baseline (138.934 us; speedup 1.0000x reference)
//
#include <hip/hip_runtime.h>
#include <cstdint>
#include <cstddef>

typedef unsigned short u16;
typedef float f32x4 __attribute__((ext_vector_type(4)));
typedef short short8 __attribute__((ext_vector_type(8)));
typedef u16 u16x4 __attribute__((ext_vector_type(4)));
typedef unsigned u32x4 __attribute__((ext_vector_type(4)));

// D = A*B + C  (16x16x32 bf16, fp32 acc).  A-frag: row=lane&15, k=(lane>>4)*8+e
// B-frag: col=lane&15, k=(lane>>4)*8+e.   C/D: col=lane&15, row=(lane>>4)*4+reg.
#define MFMA_BF16(acc, a, b) \
  asm("v_mfma_f32_16x16x32_bf16 %0, %1, %2, %0" : "+v"(acc) : "v"(a), "v"(b))

// async global->LDS, 16B per lane; LDS dest = wave-uniform base + lane*16
#define GLDS16(gp, lp) __builtin_amdgcn_global_load_lds( \
    (__attribute__((address_space(1))) void*)(void*)(uintptr_t)(gp), \
    (__attribute__((address_space(3))) void*)(lp), 16, 0, 0)

static __device__ __forceinline__ u16 f2bf(float f) {
  union { float f; unsigned u; } x; x.f = f;
  unsigned u = x.u + 0x7fffu + ((x.u >> 16) & 1u);
  return (u16)(u >> 16);
}

// ---------------- elementwise f32 -> bf16 ----------------
__global__ __launch_bounds__(256) void cvt_kernel(const float* __restrict__ src,
                                                  u16* __restrict__ dst, int n4) {
  int stride = gridDim.x * 256;
  for (int i = blockIdx.x * 256 + threadIdx.x; i < n4; i += stride) {
    f32x4 v = ((const f32x4*)src)[i];
    u16x4 o;
    o[0] = f2bf(v[0]); o[1] = f2bf(v[1]); o[2] = f2bf(v[2]); o[3] = f2bf(v[3]);
    ((u16x4*)dst)[i] = o;
  }
}

// ---------------- transpose + convert: dst[c][r] = bf16(src[r][c] * (c<sclim ? 0.125 : 1)) ----
__global__ __launch_bounds__(256) void tcvt_kernel(const float* __restrict__ src,
                                                   u16* __restrict__ dst, int R, int C,
                                                   int sclim) {
  __shared__ float tile[64][65];
  int c0 = blockIdx.x * 64, r0 = blockIdx.y * 64;
  for (int t = threadIdx.x; t < 4096; t += 256) {
    int r = t >> 6, c = t & 63;
    tile[r][c] = src[(size_t)(r0 + r) * C + c0 + c];
  }
  __syncthreads();
  for (int t = threadIdx.x; t < 4096; t += 256) {
    int rr = t >> 6, cc = t & 63;
    float sc = (c0 + rr) < sclim ? 0.125f : 1.0f;
    dst[(size_t)(c0 + rr) * R + r0 + cc] = f2bf(tile[cc][rr] * sc);
  }
}

// ---------------- GEMM1: qkv = x_bf16[16384,512] @ WqkvT[1536,512]^T ----------------
// cols 0..1023 -> qk buffer [16384][1024] (q pre-scaled by 0.125 via Wqkv);
// cols 1024..1535 (v) -> vT[b*512+d][1024] transposed
__global__ __launch_bounds__(256) void gemm_qkv_kernel(const u16* __restrict__ A,
                                                       const u16* __restrict__ BT,
                                                       u16* __restrict__ qk,
                                                       u16* __restrict__ vT) {
  __shared__ u16 As[128 * 64];
  __shared__ u16 Bs[128 * 64];
  const int tid = threadIdx.x, lane = tid & 63, wave = tid >> 6;
  const int wr = wave >> 1, wc = wave & 1;
  const int m0 = blockIdx.y * 128, n0 = blockIdx.x * 128;
  f32x4 acc[4][4] = {};
  for (int kt = 0; kt < 8; ++kt) {
    int k0 = kt * 64;
    __syncthreads();
    #pragma unroll
    for (int t = 0; t < 4; ++t) {
      int ch = wave * 4 + t;
      GLDS16(A + (size_t)(m0 + ch * 8 + (lane >> 3)) * 512 + k0 + (lane & 7) * 8, &As[ch * 512]);
      GLDS16(BT + (size_t)(n0 + ch * 8 + (lane >> 3)) * 512 + k0 + (lane & 7) * 8, &Bs[ch * 512]);
    }
    __syncthreads();
    #pragma unroll
    for (int kk = 0; kk < 2; ++kk) {
      short8 af[4], bfr[4];
      #pragma unroll
      for (int m = 0; m < 4; ++m)
        af[m] = *(const short8*)&As[(wr * 64 + m * 16 + (lane & 15)) * 64 + kk * 32 + (lane >> 4) * 8];
      #pragma unroll
      for (int n = 0; n < 4; ++n)
        bfr[n] = *(const short8*)&Bs[(wc * 64 + n * 16 + (lane & 15)) * 64 + kk * 32 + (lane >> 4) * 8];
      #pragma unroll
      for (int m = 0; m < 4; ++m)
        #pragma unroll
        for (int n = 0; n < 4; ++n)
          MFMA_BF16(acc[m][n], af[m], bfr[n]);
    }
  }
  const int row0 = m0 + wr * 64, col0 = n0 + wc * 64;
  if (n0 < 1024) {
    #pragma unroll
    for (int m = 0; m < 4; ++m) {
      int row = row0 + m * 16 + (lane >> 4) * 4;
      #pragma unroll
      for (int n = 0; n < 4; ++n) {
        int col = col0 + n * 16 + (lane & 15);
        #pragma unroll
        for (int i = 0; i < 4; ++i)
          qk[(size_t)(row + i) * 1024 + col] = f2bf(acc[m][n][i]);
      }
    }
  } else {
    #pragma unroll
    for (int m = 0; m < 4; ++m) {
      int row = row0 + m * 16 + (lane >> 4) * 4;   // global token index
      int bb = row >> 10, nn = row & 1023;
      #pragma unroll
      for (int n = 0; n < 4; ++n) {
        int d = col0 + n * 16 + (lane & 15) - 1024;  // 0..511
        u16x4 pk;
        #pragma unroll
        for (int i = 0; i < 4; ++i) pk[i] = f2bf(acc[m][n][i]);
        *(u16x4*)&vT[(size_t)(bb * 512 + d) * 1024 + nn] = pk;
      }
    }
  }
}

// ---------------- attention: O = relu(Q K^T) @ V  (scale pre-folded into Q) ----------------
// Swapped QK^T (mfma(K,Q)) -> lane (g,lo) holds S[i=lo][j=n*16+g*4+r].  PV's A-frag
// needs S[i=lo][j=g*8+e]: assembled IN REGISTERS via 8 __shfl + 4 cndmask per (c,m)
// (src lanes ((g&1)*2+s)*16+lo, chunk select by g>>1).  No S LDS round trip.
// K/V double-buffered (2x16KB), staging for jt+1 issued before compute of jt;
// single __syncthreads per jt (its vmcnt(0) drains the prefetch after compute).
// Wave owns 32 q-rows, full j.  Only verified 16x16x32 MFMA used.
__global__ __launch_bounds__(256) void attn_kernel(const u16* __restrict__ qk,
                                                   const u16* __restrict__ vT,
                                                   float* __restrict__ aout) {
  __shared__ u16 smem[16384];          // 32 KB: buf{0,1} x [Ks 64x64 | Vs 64x64]
  const int tid = threadIdx.x, lane = tid & 63, wave = tid >> 6;
  const int g = lane >> 4, lo = lane & 15;
  const int krow = lane >> 3, kslot = lane & 7;      // staging lane decomposition
  const int L = blockIdx.x;
  const int qt = L >> 7, bh = L & 127, h = bh & 7, b = bh >> 3;
  const size_t qrow0 = (size_t)b * 1024 + qt * 128;
  const u16* Kg0 = qk + (size_t)b * 1024 * 1024 + 512 + h * 64;   // [token][512+h*64+d]
  const u16* Vg0 = vT + ((size_t)b * 512 + h * 64) * 1024;        // [d][token]

  short8 qf[2][2];
  #pragma unroll
  for (int m = 0; m < 2; ++m)
    #pragma unroll
    for (int kk = 0; kk < 2; ++kk)
      qf[m][kk] = *(const short8*)&qk[(qrow0 + wave * 32 + m * 16 + lo) * 1024
                                      + h * 64 + kk * 32 + g * 8];

  const int srcA = ((g & 1) * 2) * 16 + lo;          // shuffle source lanes
  const int srcB = srcA + 16;

  f32x4 acc[2][4] = {};                // O: i = wave*32+m*16+g*4+r, d = t*16+lo

  // prologue: stage jt=0 into buf0
  #pragma unroll
  for (int t = 0; t < 2; ++t) {
    int ch = wave * 2 + t;             // 8 chunks of 8 rows
    GLDS16(Kg0 + (size_t)(ch * 8 + krow) * 1024 + (kslot ^ krow) * 8, &smem[ch * 512]);
    GLDS16(Vg0 + (size_t)(ch * 8 + krow) * 1024 + (kslot ^ krow) * 8, &smem[4096 + ch * 512]);
  }
  int cur = 0;
  for (int jt = 0; jt < 16; ++jt) {
    __syncthreads();                   // buf(cur) staged; all prev reads done
    if (jt < 15) {                     // prefetch jt+1 into buf(cur^1)
      const u16* Kg = Kg0 + (size_t)(jt + 1) * 64 * 1024;
      const u16* Vg = Vg0 + (jt + 1) * 64;
      u16* nb = &smem[(cur ^ 1) * 8192];
      #pragma unroll
      for (int t = 0; t < 2; ++t) {
        int ch = wave * 2 + t;
        GLDS16(Kg + (size_t)(ch * 8 + krow) * 1024 + (kslot ^ krow) * 8, &nb[ch * 512]);
        GLDS16(Vg + (size_t)(ch * 8 + krow) * 1024 + (kslot ^ krow) * 8, &nb[4096 + ch * 512]);
      }
    }
    const u16* Ks = &smem[cur * 8192];
    const u16* Vs = &smem[cur * 8192 + 4096];
    // QK^T (swapped): sacc[n][m] = S[i=lo (+m*16)][j = jt*64 + n*16 + g*4 + r]
    f32x4 sacc[4][2] = {};
    __builtin_amdgcn_s_setprio(1);
    #pragma unroll
    for (int kk = 0; kk < 2; ++kk)
      #pragma unroll
      for (int n = 0; n < 4; ++n) {
        int r = n * 16 + lo;
        short8 kf = *(const short8*)&Ks[r * 64 + (((kk * 4 + g) ^ (lo & 7)) * 8)];
        #pragma unroll
        for (int m = 0; m < 2; ++m)
          MFMA_BF16(sacc[n][m], kf, qf[m][kk]);
      }
    __builtin_amdgcn_s_setprio(0);
    // relu + pack pairs: pk[n][m][0] = bf16x2(r0,r1), [1] = bf16x2(r2,r3)
    unsigned pk[4][2][2];
    #pragma unroll
    for (int n = 0; n < 4; ++n)
      #pragma unroll
      for (int m = 0; m < 2; ++m) {
        float a0 = fmaxf(sacc[n][m][0], 0.f), a1 = fmaxf(sacc[n][m][1], 0.f);
        float a2 = fmaxf(sacc[n][m][2], 0.f), a3 = fmaxf(sacc[n][m][3], 0.f);
        asm("v_cvt_pk_bf16_f32 %0, %1, %2" : "=v"(pk[n][m][0]) : "v"(a0), "v"(a1));
        asm("v_cvt_pk_bf16_f32 %0, %1, %2" : "=v"(pk[n][m][1]) : "v"(a2), "v"(a3));
      }
    // PV: assemble pa (A-frag S[i=lo][j=c*32+g*8+e]) by lane shuffles, then MFMA
    __builtin_amdgcn_s_setprio(1);
    #pragma unroll
    for (int c = 0; c < 2; ++c) {
      u32x4 paw[2];
      #pragma unroll
      for (int m = 0; m < 2; ++m)
        #pragma unroll
        for (int w = 0; w < 4; ++w) {
          int src = (w >> 1) ? srcB : srcA;
          unsigned tA = (unsigned)__shfl((int)pk[2 * c][m][w & 1], src);
          unsigned tB = (unsigned)__shfl((int)pk[2 * c + 1][m][w & 1], src);
          paw[m][w] = (g >> 1) ? tB : tA;
        }
      #pragma unroll
      for (int t = 0; t < 4; ++t) {
        int d = t * 16 + lo;
        short8 vb = *(const short8*)&Vs[d * 64 + (((c * 4 + g) ^ (lo & 7)) * 8)];
        #pragma unroll
        for (int m = 0; m < 2; ++m) {
          short8 pa = *(short8*)&paw[m];
          MFMA_BF16(acc[m][t], pa, vb);
        }
      }
    }
    __builtin_amdgcn_s_setprio(0);
    cur ^= 1;
  }
  #pragma unroll
  for (int m = 0; m < 2; ++m)
    #pragma unroll
    for (int t = 0; t < 4; ++t)
      #pragma unroll
      for (int r = 0; r < 4; ++r)
        aout[(qrow0 + wave * 32 + m * 16 + g * 4 + r) * 512 + h * 64 + t * 16 + lo]
            = acc[m][t][r];
}

// ---------------- LayerNorm over 512, one wave per row, fp32 in -> bf16 out ----------------
__global__ __launch_bounds__(256) void ln_kernel(const float* __restrict__ x,
                                                 const float* __restrict__ g,
                                                 const float* __restrict__ bt,
                                                 u16* __restrict__ y) {
  const int lane = threadIdx.x & 63, wave = threadIdx.x >> 6;
  const size_t row = (size_t)blockIdx.x * 4 + wave;
  const float* xr = x + row * 512;
  f32x4 v0 = *(const f32x4*)&xr[lane * 4];
  f32x4 v1 = *(const f32x4*)&xr[256 + lane * 4];
  float s = v0[0] + v0[1] + v0[2] + v0[3] + v1[0] + v1[1] + v1[2] + v1[3];
  float q = v0[0]*v0[0] + v0[1]*v0[1] + v0[2]*v0[2] + v0[3]*v0[3]
          + v1[0]*v1[0] + v1[1]*v1[1] + v1[2]*v1[2] + v1[3]*v1[3];
  #pragma unroll
  for (int o = 32; o > 0; o >>= 1) { s += __shfl_xor(s, o); q += __shfl_xor(q, o); }
  float mean = s * (1.f / 512.f);
  float var  = q * (1.f / 512.f) - mean * mean;
  float rstd = rsqrtf(var + 1e-5f);
  f32x4 g0 = *(const f32x4*)&g[lane * 4],  g1 = *(const f32x4*)&g[256 + lane * 4];
  f32x4 b0 = *(const f32x4*)&bt[lane * 4], b1 = *(const f32x4*)&bt[256 + lane * 4];
  u16x4 o0, o1;
  #pragma unroll
  for (int i = 0; i < 4; ++i) {
    o0[i] = f2bf((v0[i] - mean) * rstd * g0[i] + b0[i]);
    o1[i] = f2bf((v1[i] - mean) * rstd * g1[i] + b1[i]);
  }
  *(u16x4*)&y[row * 512 + lane * 4] = o0;
  *(u16x4*)&y[row * 512 + 256 + lane * 4] = o1;
}

// ---------------- GEMM2: out = ln_bf16[16384,512] @ WoT[512,512]^T + bo (fp32 out) ----------------
__global__ __launch_bounds__(256) void gemm_out_kernel(const u16* __restrict__ A,
                                                       const u16* __restrict__ BT,
                                                       const float* __restrict__ bias,
                                                       float* __restrict__ out) {
  __shared__ u16 As[128 * 64];
  __shared__ u16 Bs[128 * 64];
  const int tid = threadIdx.x, lane = tid & 63, wave = tid >> 6;
  const int wr = wave >> 1, wc = wave & 1;
  const int m0 = blockIdx.y * 128, n0 = blockIdx.x * 128;
  f32x4 acc[4][4] = {};
  for (int kt = 0; kt < 8; ++kt) {
    int k0 = kt * 64;
    __syncthreads();
    #pragma unroll
    for (int t = 0; t < 4; ++t) {
      int ch = wave * 4 + t;
      GLDS16(A + (size_t)(m0 + ch * 8 + (lane >> 3)) * 512 + k0 + (lane & 7) * 8, &As[ch * 512]);
      GLDS16(BT + (size_t)(n0 + ch * 8 + (lane >> 3)) * 512 + k0 + (lane & 7) * 8, &Bs[ch * 512]);
    }
    __syncthreads();
    #pragma unroll
    for (int kk = 0; kk < 2; ++kk) {
      short8 af[4], bfr[4];
      #pragma unroll
      for (int m = 0; m < 4; ++m)
        af[m] = *(const short8*)&As[(wr * 64 + m * 16 + (lane & 15)) * 64 + kk * 32 + (lane >> 4) * 8];
      #pragma unroll
      for (int n = 0; n < 4; ++n)
        bfr[n] = *(const short8*)&Bs[(wc * 64 + n * 16 + (lane & 15)) * 64 + kk * 32 + (lane >> 4) * 8];
      #pragma unroll
      for (int m = 0; m < 4; ++m)
        #pragma unroll
        for (int n = 0; n < 4; ++n)
          MFMA_BF16(acc[m][n], af[m], bfr[n]);
    }
  }
  const int row0 = m0 + wr * 64, col0 = n0 + wc * 64;
  #pragma unroll
  for (int m = 0; m < 4; ++m) {
    int row = row0 + m * 16 + (lane >> 4) * 4;
    #pragma unroll
    for (int n = 0; n < 4; ++n) {
      int col = col0 + n * 16 + (lane & 15);
      float bv = bias[col];
      #pragma unroll
      for (int i = 0; i < 4; ++i)
        out[(size_t)(row + i) * 512 + col] = acc[m][n][i] + bv;
    }
  }
}

extern "C" void kernel_launch(void* const* d_in, const int* in_sizes, int n_in,
                              void* d_out, int out_size, void* d_ws, size_t ws_size,
                              hipStream_t stream) {
  const float* x    = (const float*)d_in[0];
  const float* Wqkv = (const float*)d_in[1];
  const float* ln_g = (const float*)d_in[2];
  const float* ln_b = (const float*)d_in[3];
  const float* Wo   = (const float*)d_in[4];
  const float* bo   = (const float*)d_in[5];
  float* out = (float*)d_out;
  char* ws = (char*)d_ws;

  u16*   xbf   = (u16*)(ws);                               // 16 MB  [16384][512], reused for LN out
  u16*   wqkvt = (u16*)(ws + 16777216);                    // 1.5 MB [1536][512]
  u16*   wot   = (u16*)(ws + 18350080);                    // 0.5 MB [512][512]
  u16*   qkb   = (u16*)(ws + 18874368);                    // 32 MB  [16384][1024]
  u16*   vtb   = (u16*)(ws + 52428800);                    // 16 MB  [b*512+d][1024]
  float* att   = (float*)(ws + 69206016);                  // 32 MB  [16384][512]

  cvt_kernel<<<4096, 256, 0, stream>>>(x, xbf, 8388608 / 4);
  tcvt_kernel<<<dim3(24, 8), 256, 0, stream>>>(Wqkv, wqkvt, 512, 1536, 512);
  tcvt_kernel<<<dim3(8, 8), 256, 0, stream>>>(Wo, wot, 512, 512, 0);
  gemm_qkv_kernel<<<dim3(12, 128), 256, 0, stream>>>(xbf, wqkvt, qkb, vtb);
  attn_kernel<<<1024, 256, 0, stream>>>(qkb, vtb, att);
  ln_kernel<<<4096, 256, 0, stream>>>(att, ln_g, ln_b, xbf);
  gemm_out_kernel<<<dim3(4, 128), 256, 0, stream>>>(xbf, wot, bo, out);
}

// Round 9
// 136.934 us; speedup vs baseline: 1.0146x; 1.0146x over previous
//
#include <hip/hip_runtime.h>
#include <cstdint>
#include <cstddef>

typedef unsigned short u16;
typedef float f32x4 __attribute__((ext_vector_type(4)));
typedef short short8 __attribute__((ext_vector_type(8)));
typedef u16 u16x4 __attribute__((ext_vector_type(4)));

// D = A*B + C  (16x16x32 bf16, fp32 acc).  A-frag: row=lane&15, k=(lane>>4)*8+e
// B-frag: col=lane&15, k=(lane>>4)*8+e.   C/D: col=lane&15, row=(lane>>4)*4+reg.
// The ONLY MFMA shape verified on this chip in this session; 16x16x16 NaNs,
// 32x32x16 produced finite-wrong output twice (rounds 7/8) — both banned.
#define MFMA_BF16(acc, a, b) \
  asm("v_mfma_f32_16x16x32_bf16 %0, %1, %2, %0" : "+v"(acc) : "v"(a), "v"(b))

// async global->LDS, 16B per lane; LDS dest = wave-uniform base + lane*16
#define GLDS16(gp, lp) __builtin_amdgcn_global_load_lds( \
    (__attribute__((address_space(1))) void*)(void*)(uintptr_t)(gp), \
    (__attribute__((address_space(3))) void*)(lp), 16, 0, 0)

static __device__ __forceinline__ u16 f2bf(float f) {
  union { float f; unsigned u; } x; x.f = f;
  unsigned u = x.u + 0x7fffu + ((x.u >> 16) & 1u);
  return (u16)(u >> 16);
}

// ---------------- elementwise f32 -> bf16 ----------------
__global__ __launch_bounds__(256) void cvt_kernel(const float* __restrict__ src,
                                                  u16* __restrict__ dst, int n4) {
  int stride = gridDim.x * 256;
  for (int i = blockIdx.x * 256 + threadIdx.x; i < n4; i += stride) {
    f32x4 v = ((const f32x4*)src)[i];
    u16x4 o;
    o[0] = f2bf(v[0]); o[1] = f2bf(v[1]); o[2] = f2bf(v[2]); o[3] = f2bf(v[3]);
    ((u16x4*)dst)[i] = o;
  }
}

// ---------------- transpose + convert: dst[c][r] = bf16(src[r][c] * (c<sclim ? 0.125 : 1)) ----
__global__ __launch_bounds__(256) void tcvt_kernel(const float* __restrict__ src,
                                                   u16* __restrict__ dst, int R, int C,
                                                   int sclim) {
  __shared__ float tile[64][65];
  int c0 = blockIdx.x * 64, r0 = blockIdx.y * 64;
  for (int t = threadIdx.x; t < 4096; t += 256) {
    int r = t >> 6, c = t & 63;
    tile[r][c] = src[(size_t)(r0 + r) * C + c0 + c];
  }
  __syncthreads();
  for (int t = threadIdx.x; t < 4096; t += 256) {
    int rr = t >> 6, cc = t & 63;
    float sc = (c0 + rr) < sclim ? 0.125f : 1.0f;
    dst[(size_t)(c0 + rr) * R + r0 + cc] = f2bf(tile[cc][rr] * sc);
  }
}

// ---------------- GEMM1: qkv = x_bf16[16384,512] @ WqkvT[1536,512]^T ----------------
// cols 0..1023 -> qk buffer [16384][1024] (q pre-scaled by 0.125 via Wqkv);
// cols 1024..1535 (v) -> vT[b*512+d][1024] transposed
__global__ __launch_bounds__(256) void gemm_qkv_kernel(const u16* __restrict__ A,
                                                       const u16* __restrict__ BT,
                                                       u16* __restrict__ qk,
                                                       u16* __restrict__ vT) {
  __shared__ u16 As[128 * 64];
  __shared__ u16 Bs[128 * 64];
  const int tid = threadIdx.x, lane = tid & 63, wave = tid >> 6;
  const int wr = wave >> 1, wc = wave & 1;
  const int m0 = blockIdx.y * 128, n0 = blockIdx.x * 128;
  f32x4 acc[4][4] = {};
  for (int kt = 0; kt < 8; ++kt) {
    int k0 = kt * 64;
    __syncthreads();
    #pragma unroll
    for (int t = 0; t < 4; ++t) {
      int ch = wave * 4 + t;
      GLDS16(A + (size_t)(m0 + ch * 8 + (lane >> 3)) * 512 + k0 + (lane & 7) * 8, &As[ch * 512]);
      GLDS16(BT + (size_t)(n0 + ch * 8 + (lane >> 3)) * 512 + k0 + (lane & 7) * 8, &Bs[ch * 512]);
    }
    __syncthreads();
    #pragma unroll
    for (int kk = 0; kk < 2; ++kk) {
      short8 af[4], bfr[4];
      #pragma unroll
      for (int m = 0; m < 4; ++m)
        af[m] = *(const short8*)&As[(wr * 64 + m * 16 + (lane & 15)) * 64 + kk * 32 + (lane >> 4) * 8];
      #pragma unroll
      for (int n = 0; n < 4; ++n)
        bfr[n] = *(const short8*)&Bs[(wc * 64 + n * 16 + (lane & 15)) * 64 + kk * 32 + (lane >> 4) * 8];
      #pragma unroll
      for (int m = 0; m < 4; ++m)
        #pragma unroll
        for (int n = 0; n < 4; ++n)
          MFMA_BF16(acc[m][n], af[m], bfr[n]);
    }
  }
  const int row0 = m0 + wr * 64, col0 = n0 + wc * 64;
  if (n0 < 1024) {
    #pragma unroll
    for (int m = 0; m < 4; ++m) {
      int row = row0 + m * 16 + (lane >> 4) * 4;
      #pragma unroll
      for (int n = 0; n < 4; ++n) {
        int col = col0 + n * 16 + (lane & 15);
        #pragma unroll
        for (int i = 0; i < 4; ++i)
          qk[(size_t)(row + i) * 1024 + col] = f2bf(acc[m][n][i]);
      }
    }
  } else {
    #pragma unroll
    for (int m = 0; m < 4; ++m) {
      int row = row0 + m * 16 + (lane >> 4) * 4;   // global token index
      int bb = row >> 10, nn = row & 1023;
      #pragma unroll
      for (int n = 0; n < 4; ++n) {
        int d = col0 + n * 16 + (lane & 15) - 1024;  // 0..511
        u16x4 pk;
        #pragma unroll
        for (int i = 0; i < 4; ++i) pk[i] = f2bf(acc[m][n][i]);
        *(u16x4*)&vT[(size_t)(bb * 512 + d) * 1024 + nn] = pk;
      }
    }
  }
}

// ---------------- attention: O = relu(Q K^T) @ V  (scale pre-folded into Q) ----------------
// Round-5-verified core (S through LDS, 16x16x32 MFMA only), linear grid w/
// XCD-local decode (bh = L&127), setprio around MFMA clusters.
__global__ __launch_bounds__(256) void attn_kernel(const u16* __restrict__ qk,
                                                   const u16* __restrict__ vT,
                                                   float* __restrict__ aout) {
  __shared__ u16 smem[24576];          // 49152 B -> 3 blocks/CU
  u16* Ks = smem;                      // [128][64]  (aliased by Ss, barrier-separated)
  u16* Ss = smem;                      // [128][128] swizzled S
  u16* Vs = smem + 16384;              // [64][128]  V^T tile
  const int tid = threadIdx.x, lane = tid & 63, wave = tid >> 6;
  const int wr = wave >> 1, wc = wave & 1;
  const int L = blockIdx.x;
  const int qt = L >> 7, bh = L & 127, h = bh & 7, b = bh >> 3;
  const size_t qrow0 = (size_t)b * 1024 + qt * 128;

  short8 qf[4][2];
  #pragma unroll
  for (int m = 0; m < 4; ++m)
    #pragma unroll
    for (int kk = 0; kk < 2; ++kk)
      qf[m][kk] = *(const short8*)&qk[(qrow0 + wr * 64 + m * 16 + (lane & 15)) * 1024
                                      + h * 64 + kk * 32 + (lane >> 4) * 8];
  f32x4 acc[4][2] = {};
  for (int jt = 0; jt < 8; ++jt) {
    __syncthreads();                                         // prev PV reads done
    const u16* Kg = qk + ((size_t)b * 1024 + jt * 128) * 1024 + 512 + h * 64;
    const u16* Vg = vT + ((size_t)b * 512 + h * 64) * 1024 + jt * 128;
    #pragma unroll
    for (int t = 0; t < 4; ++t) {
      int ch = wave * 4 + t;
      GLDS16(Kg + (size_t)(ch * 8 + (lane >> 3)) * 1024 + ((lane & 7) ^ (lane >> 3)) * 8,
             &Ks[ch * 512]);
      GLDS16(Vg + (size_t)(ch * 4 + (lane >> 4)) * 1024 + ((lane & 15) ^ (t * 4 + (lane >> 4))) * 8,
             &Vs[ch * 512]);
    }
    __syncthreads();                                         // K,V staged
    // S^T = K.Q^T : sacc[n][m] tile has row=j_local, col=i_local
    f32x4 sacc[4][4] = {};
    __builtin_amdgcn_s_setprio(1);
    #pragma unroll
    for (int kk = 0; kk < 2; ++kk) {
      short8 kf[4];
      #pragma unroll
      for (int n = 0; n < 4; ++n) {
        int r = wc * 64 + n * 16 + (lane & 15);
        int slot = kk * 4 + (lane >> 4);                     // 0..7
        kf[n] = *(const short8*)&Ks[r * 64 + ((slot ^ (r & 7)) * 8)];
      }
      #pragma unroll
      for (int n = 0; n < 4; ++n)
        #pragma unroll
        for (int m = 0; m < 4; ++m)
          MFMA_BF16(sacc[n][m], kf[n], qf[m][kk]);
    }
    __builtin_amdgcn_s_setprio(0);
    __syncthreads();                                         // K reads done (Ss aliases Ks)
    #pragma unroll
    for (int m = 0; m < 4; ++m) {
      int i = wr * 64 + m * 16 + (lane & 15);
      unsigned rowbase = (unsigned)i * 256;                  // byte offset of S row
      unsigned sw = (unsigned)(i & 15) << 4;
      #pragma unroll
      for (int n = 0; n < 4; ++n) {
        int j0 = wc * 64 + n * 16 + (lane >> 4) * 4;
        u16x4 pk;
        #pragma unroll
        for (int r = 0; r < 4; ++r) pk[r] = f2bf(fmaxf(sacc[n][m][r], 0.f));
        *(u16x4*)((char*)Ss + (rowbase + (((unsigned)j0 * 2) ^ sw))) = pk;
      }
    }
    __syncthreads();                                         // S visible
    __builtin_amdgcn_s_setprio(1);
    #pragma unroll
    for (int ks = 0; ks < 4; ++ks) {
      short8 sa[4], vb[2];
      #pragma unroll
      for (int m = 0; m < 4; ++m) {
        int i = wr * 64 + m * 16 + (lane & 15);
        unsigned c2 = (unsigned)(ks * 32 + (lane >> 4) * 8) * 2;
        sa[m] = *(const short8*)((const char*)Ss + (unsigned)i * 256 + (c2 ^ ((unsigned)(i & 15) << 4)));
      }
      #pragma unroll
      for (int n = 0; n < 2; ++n) {
        int r = wc * 32 + n * 16 + (lane & 15);
        int slot = ks * 4 + (lane >> 4);                     // 0..15
        vb[n] = *(const short8*)&Vs[r * 128 + ((slot ^ (r & 15)) * 8)];
      }
      #pragma unroll
      for (int m = 0; m < 4; ++m)
        #pragma unroll
        for (int n = 0; n < 2; ++n)
          MFMA_BF16(acc[m][n], sa[m], vb[n]);
    }
    __builtin_amdgcn_s_setprio(0);
  }
  #pragma unroll
  for (int m = 0; m < 4; ++m) {
    int row = wr * 64 + m * 16 + (lane >> 4) * 4;
    #pragma unroll
    for (int n = 0; n < 2; ++n) {
      int col = h * 64 + wc * 32 + n * 16 + (lane & 15);
      #pragma unroll
      for (int i = 0; i < 4; ++i)
        aout[(qrow0 + row + i) * 512 + col] = acc[m][n][i];
    }
  }
}

// ---------------- LayerNorm over 512, one wave per row, fp32 in -> bf16 out ----------------
__global__ __launch_bounds__(256) void ln_kernel(const float* __restrict__ x,
                                                 const float* __restrict__ g,
                                                 const float* __restrict__ bt,
                                                 u16* __restrict__ y) {
  const int lane = threadIdx.x & 63, wave = threadIdx.x >> 6;
  const size_t row = (size_t)blockIdx.x * 4 + wave;
  const float* xr = x + row * 512;
  f32x4 v0 = *(const f32x4*)&xr[lane * 4];
  f32x4 v1 = *(const f32x4*)&xr[256 + lane * 4];
  float s = v0[0] + v0[1] + v0[2] + v0[3] + v1[0] + v1[1] + v1[2] + v1[3];
  float q = v0[0]*v0[0] + v0[1]*v0[1] + v0[2]*v0[2] + v0[3]*v0[3]
          + v1[0]*v1[0] + v1[1]*v1[1] + v1[2]*v1[2] + v1[3]*v1[3];
  #pragma unroll
  for (int o = 32; o > 0; o >>= 1) { s += __shfl_xor(s, o); q += __shfl_xor(q, o); }
  float mean = s * (1.f / 512.f);
  float var  = q * (1.f / 512.f) - mean * mean;
  float rstd = rsqrtf(var + 1e-5f);
  f32x4 g0 = *(const f32x4*)&g[lane * 4],  g1 = *(const f32x4*)&g[256 + lane * 4];
  f32x4 b0 = *(const f32x4*)&bt[lane * 4], b1 = *(const f32x4*)&bt[256 + lane * 4];
  u16x4 o0, o1;
  #pragma unroll
  for (int i = 0; i < 4; ++i) {
    o0[i] = f2bf((v0[i] - mean) * rstd * g0[i] + b0[i]);
    o1[i] = f2bf((v1[i] - mean) * rstd * g1[i] + b1[i]);
  }
  *(u16x4*)&y[row * 512 + lane * 4] = o0;
  *(u16x4*)&y[row * 512 + 256 + lane * 4] = o1;
}

// ---------------- GEMM2: out = ln_bf16[16384,512] @ WoT[512,512]^T + bo (fp32 out) ----------------
__global__ __launch_bounds__(256) void gemm_out_kernel(const u16* __restrict__ A,
                                                       const u16* __restrict__ BT,
                                                       const float* __restrict__ bias,
                                                       float* __restrict__ out) {
  __shared__ u16 As[128 * 64];
  __shared__ u16 Bs[128 * 64];
  const int tid = threadIdx.x, lane = tid & 63, wave = tid >> 6;
  const int wr = wave >> 1, wc = wave & 1;
  const int m0 = blockIdx.y * 128, n0 = blockIdx.x * 128;
  f32x4 acc[4][4] = {};
  for (int kt = 0; kt < 8; ++kt) {
    int k0 = kt * 64;
    __syncthreads();
    #pragma unroll
    for (int t = 0; t < 4; ++t) {
      int ch = wave * 4 + t;
      GLDS16(A + (size_t)(m0 + ch * 8 + (lane >> 3)) * 512 + k0 + (lane & 7) * 8, &As[ch * 512]);
      GLDS16(BT + (size_t)(n0 + ch * 8 + (lane >> 3)) * 512 + k0 + (lane & 7) * 8, &Bs[ch * 512]);
    }
    __syncthreads();
    #pragma unroll
    for (int kk = 0; kk < 2; ++kk) {
      short8 af[4], bfr[4];
      #pragma unroll
      for (int m = 0; m < 4; ++m)
        af[m] = *(const short8*)&As[(wr * 64 + m * 16 + (lane & 15)) * 64 + kk * 32 + (lane >> 4) * 8];
      #pragma unroll
      for (int n = 0; n < 4; ++n)
        bfr[n] = *(const short8*)&Bs[(wc * 64 + n * 16 + (lane & 15)) * 64 + kk * 32 + (lane >> 4) * 8];
      #pragma unroll
      for (int m = 0; m < 4; ++m)
        #pragma unroll
        for (int n = 0; n < 4; ++n)
          MFMA_BF16(acc[m][n], af[m], bfr[n]);
    }
  }
  const int row0 = m0 + wr * 64, col0 = n0 + wc * 64;
  #pragma unroll
  for (int m = 0; m < 4; ++m) {
    int row = row0 + m * 16 + (lane >> 4) * 4;
    #pragma unroll
    for (int n = 0; n < 4; ++n) {
      int col = col0 + n * 16 + (lane & 15);
      float bv = bias[col];
      #pragma unroll
      for (int i = 0; i < 4; ++i)
        out[(size_t)(row + i) * 512 + col] = acc[m][n][i] + bv;
    }
  }
}

extern "C" void kernel_launch(void* const* d_in, const int* in_sizes, int n_in,
                              void* d_out, int out_size, void* d_ws, size_t ws_size,
                              hipStream_t stream) {
  const float* x    = (const float*)d_in[0];
  const float* Wqkv = (const float*)d_in[1];
  const float* ln_g = (const float*)d_in[2];
  const float* ln_b = (const float*)d_in[3];
  const float* Wo   = (const float*)d_in[4];
  const float* bo   = (const float*)d_in[5];
  float* out = (float*)d_out;
  char* ws = (char*)d_ws;

  u16*   xbf   = (u16*)(ws);                               // 16 MB  [16384][512], reused for LN out
  u16*   wqkvt = (u16*)(ws + 16777216);                    // 1.5 MB [1536][512]
  u16*   wot   = (u16*)(ws + 18350080);                    // 0.5 MB [512][512]
  u16*   qkb   = (u16*)(ws + 18874368);                    // 32 MB  [16384][1024]
  u16*   vtb   = (u16*)(ws + 52428800);                    // 16 MB  [b*512+d][1024]
  float* att   = (float*)(ws + 69206016);                  // 32 MB  [16384][512]

  cvt_kernel<<<4096, 256, 0, stream>>>(x, xbf, 8388608 / 4);
  tcvt_kernel<<<dim3(24, 8), 256, 0, stream>>>(Wqkv, wqkvt, 512, 1536, 512);
  tcvt_kernel<<<dim3(8, 8), 256, 0, stream>>>(Wo, wot, 512, 512, 0);
  gemm_qkv_kernel<<<dim3(12, 128), 256, 0, stream>>>(xbf, wqkvt, qkb, vtb);
  attn_kernel<<<1024, 256, 0, stream>>>(qkb, vtb, att);
  ln_kernel<<<4096, 256, 0, stream>>>(att, ln_g, ln_b, xbf);
  gemm_out_kernel<<<dim3(4, 128), 256, 0, stream>>>(xbf, wot, bo, out);
}

// Round 10
// 130.843 us; speedup vs baseline: 1.0618x; 1.0465x over previous
//
#include <hip/hip_runtime.h>
#include <cstdint>
#include <cstddef>

typedef unsigned short u16;
typedef float f32x4 __attribute__((ext_vector_type(4)));
typedef short short8 __attribute__((ext_vector_type(8)));
typedef u16 u16x4 __attribute__((ext_vector_type(4)));

// D = A*B + C  (16x16x32 bf16, fp32 acc).  A-frag: row=lane&15, k=(lane>>4)*8+e
// B-frag: col=lane&15, k=(lane>>4)*8+e.   C/D: col=lane&15, row=(lane>>4)*4+reg.
// The ONLY MFMA shape verified on this chip in this session; 16x16x16 NaNs,
// 32x32x16 produced finite-wrong output twice (rounds 7/8) — both banned.
#define MFMA_BF16(acc, a, b) \
  asm("v_mfma_f32_16x16x32_bf16 %0, %1, %2, %0" : "+v"(acc) : "v"(a), "v"(b))

// async global->LDS, 16B per lane; LDS dest = wave-uniform base + lane*16
#define GLDS16(gp, lp) __builtin_amdgcn_global_load_lds( \
    (__attribute__((address_space(1))) void*)(void*)(uintptr_t)(gp), \
    (__attribute__((address_space(3))) void*)(lp), 16, 0, 0)

static __device__ __forceinline__ u16 f2bf(float f) {
  union { float f; unsigned u; } x; x.f = f;
  unsigned u = x.u + 0x7fffu + ((x.u >> 16) & 1u);
  return (u16)(u >> 16);
}

// ---------------- elementwise f32 -> bf16 ----------------
__global__ __launch_bounds__(256) void cvt_kernel(const float* __restrict__ src,
                                                  u16* __restrict__ dst, int n4) {
  int stride = gridDim.x * 256;
  for (int i = blockIdx.x * 256 + threadIdx.x; i < n4; i += stride) {
    f32x4 v = ((const f32x4*)src)[i];
    u16x4 o;
    o[0] = f2bf(v[0]); o[1] = f2bf(v[1]); o[2] = f2bf(v[2]); o[3] = f2bf(v[3]);
    ((u16x4*)dst)[i] = o;
  }
}

// ---------------- transpose + convert: dst[c][r] = bf16(src[r][c] * (c<sclim ? 0.125 : 1)) ----
__global__ __launch_bounds__(256) void tcvt_kernel(const float* __restrict__ src,
                                                   u16* __restrict__ dst, int R, int C,
                                                   int sclim) {
  __shared__ float tile[64][65];
  int c0 = blockIdx.x * 64, r0 = blockIdx.y * 64;
  for (int t = threadIdx.x; t < 4096; t += 256) {
    int r = t >> 6, c = t & 63;
    tile[r][c] = src[(size_t)(r0 + r) * C + c0 + c];
  }
  __syncthreads();
  for (int t = threadIdx.x; t < 4096; t += 256) {
    int rr = t >> 6, cc = t & 63;
    float sc = (c0 + rr) < sclim ? 0.125f : 1.0f;
    dst[(size_t)(c0 + rr) * R + r0 + cc] = f2bf(tile[cc][rr] * sc);
  }
}

// ---------------- GEMM1: qkv = x_bf16[16384,512] @ WqkvT[1536,512]^T ----------------
// cols 0..1023 -> qk buffer [16384][1024] (q pre-scaled by 0.125 via Wqkv);
// cols 1024..1535 (v) -> vT[b*512+d][1024] via LDS transpose (coalesced writes).
// Grid: 1D 1536, XCD-chunked decode: each XCD owns 16 consecutive m-tiles x all n.
__global__ __launch_bounds__(256) void gemm_qkv_kernel(const u16* __restrict__ A,
                                                       const u16* __restrict__ BT,
                                                       u16* __restrict__ qk,
                                                       u16* __restrict__ vT) {
  __shared__ u16 smem[16896];          // 33792 B; As=smem[0:8192], Bs=smem[8192:16384]
  u16* As = smem;
  u16* Bs = smem + 8192;
  const int tid = threadIdx.x, lane = tid & 63, wave = tid >> 6;
  const int wr = wave >> 1, wc = wave & 1;
  const int bid = blockIdx.x;
  const int lin = (bid & 7) * 192 + (bid >> 3);        // bijective: 1536 % 8 == 0
  const int my = lin / 12, nx = lin - my * 12;
  const int m0 = my * 128, n0 = nx * 128;
  f32x4 acc[4][4] = {};
  for (int kt = 0; kt < 8; ++kt) {
    int k0 = kt * 64;
    __syncthreads();
    #pragma unroll
    for (int t = 0; t < 4; ++t) {
      int ch = wave * 4 + t;
      GLDS16(A + (size_t)(m0 + ch * 8 + (lane >> 3)) * 512 + k0 + (lane & 7) * 8, &As[ch * 512]);
      GLDS16(BT + (size_t)(n0 + ch * 8 + (lane >> 3)) * 512 + k0 + (lane & 7) * 8, &Bs[ch * 512]);
    }
    __syncthreads();
    #pragma unroll
    for (int kk = 0; kk < 2; ++kk) {
      short8 af[4], bfr[4];
      #pragma unroll
      for (int m = 0; m < 4; ++m)
        af[m] = *(const short8*)&As[(wr * 64 + m * 16 + (lane & 15)) * 64 + kk * 32 + (lane >> 4) * 8];
      #pragma unroll
      for (int n = 0; n < 4; ++n)
        bfr[n] = *(const short8*)&Bs[(wc * 64 + n * 16 + (lane & 15)) * 64 + kk * 32 + (lane >> 4) * 8];
      #pragma unroll
      for (int m = 0; m < 4; ++m)
        #pragma unroll
        for (int n = 0; n < 4; ++n)
          MFMA_BF16(acc[m][n], af[m], bfr[n]);
    }
  }
  const int row0 = m0 + wr * 64, col0 = n0 + wc * 64;
  if (n0 < 1024) {
    #pragma unroll
    for (int m = 0; m < 4; ++m) {
      int row = row0 + m * 16 + (lane >> 4) * 4;
      #pragma unroll
      for (int n = 0; n < 4; ++n) {
        int col = col0 + n * 16 + (lane & 15);
        #pragma unroll
        for (int i = 0; i < 4; ++i)
          qk[(size_t)(row + i) * 1024 + col] = f2bf(acc[m][n][i]);
      }
    }
  } else {
    // V block: transpose through LDS, then coalesced global writes.
    __syncthreads();                   // all As/Bs reads done; smem reused as Td[128][132]
    const int lo = lane & 15, g = lane >> 4;
    #pragma unroll
    for (int m = 0; m < 4; ++m) {
      int tl0 = wr * 64 + m * 16 + g * 4;          // token_local base (4 consecutive)
      #pragma unroll
      for (int n = 0; n < 4; ++n) {
        int dl = wc * 64 + n * 16 + lo;            // d_local
        u16x4 pk;
        #pragma unroll
        for (int i = 0; i < 4; ++i) pk[i] = f2bf(acc[m][n][i]);
        *(u16x4*)&smem[dl * 132 + tl0] = pk;       // Td[dl][tl0..tl0+3]
      }
    }
    __syncthreads();
    const int bb = m0 >> 10, nn0 = m0 & 1023, d0 = n0 - 1024;
    for (int t = tid; t < 128 * 32; t += 256) {    // 128 d-rows x 32 8B-segs
      int d = t >> 5, sg = t & 31;
      u16x4 v = *(const u16x4*)&smem[d * 132 + sg * 4];
      *(u16x4*)&vT[(size_t)(bb * 512 + d0 + d) * 1024 + nn0 + sg * 4] = v;
    }
  }
}

// ---------------- attention: O = relu(Q K^T) @ V  (scale pre-folded into Q) ----------------
// Round-5-verified core (S through LDS, 16x16x32 MFMA only), linear grid w/
// XCD-local decode (bh = L&127), setprio around MFMA clusters.
__global__ __launch_bounds__(256) void attn_kernel(const u16* __restrict__ qk,
                                                   const u16* __restrict__ vT,
                                                   float* __restrict__ aout) {
  __shared__ u16 smem[24576];          // 49152 B -> 3 blocks/CU
  u16* Ks = smem;                      // [128][64]  (aliased by Ss, barrier-separated)
  u16* Ss = smem;                      // [128][128] swizzled S
  u16* Vs = smem + 16384;              // [64][128]  V^T tile
  const int tid = threadIdx.x, lane = tid & 63, wave = tid >> 6;
  const int wr = wave >> 1, wc = wave & 1;
  const int L = blockIdx.x;
  const int qt = L >> 7, bh = L & 127, h = bh & 7, b = bh >> 3;
  const size_t qrow0 = (size_t)b * 1024 + qt * 128;

  short8 qf[4][2];
  #pragma unroll
  for (int m = 0; m < 4; ++m)
    #pragma unroll
    for (int kk = 0; kk < 2; ++kk)
      qf[m][kk] = *(const short8*)&qk[(qrow0 + wr * 64 + m * 16 + (lane & 15)) * 1024
                                      + h * 64 + kk * 32 + (lane >> 4) * 8];
  f32x4 acc[4][2] = {};
  for (int jt = 0; jt < 8; ++jt) {
    __syncthreads();                                         // prev PV reads done
    const u16* Kg = qk + ((size_t)b * 1024 + jt * 128) * 1024 + 512 + h * 64;
    const u16* Vg = vT + ((size_t)b * 512 + h * 64) * 1024 + jt * 128;
    #pragma unroll
    for (int t = 0; t < 4; ++t) {
      int ch = wave * 4 + t;
      GLDS16(Kg + (size_t)(ch * 8 + (lane >> 3)) * 1024 + ((lane & 7) ^ (lane >> 3)) * 8,
             &Ks[ch * 512]);
      GLDS16(Vg + (size_t)(ch * 4 + (lane >> 4)) * 1024 + ((lane & 15) ^ (t * 4 + (lane >> 4))) * 8,
             &Vs[ch * 512]);
    }
    __syncthreads();                                         // K,V staged
    // S^T = K.Q^T : sacc[n][m] tile has row=j_local, col=i_local
    f32x4 sacc[4][4] = {};
    __builtin_amdgcn_s_setprio(1);
    #pragma unroll
    for (int kk = 0; kk < 2; ++kk) {
      short8 kf[4];
      #pragma unroll
      for (int n = 0; n < 4; ++n) {
        int r = wc * 64 + n * 16 + (lane & 15);
        int slot = kk * 4 + (lane >> 4);                     // 0..7
        kf[n] = *(const short8*)&Ks[r * 64 + ((slot ^ (r & 7)) * 8)];
      }
      #pragma unroll
      for (int n = 0; n < 4; ++n)
        #pragma unroll
        for (int m = 0; m < 4; ++m)
          MFMA_BF16(sacc[n][m], kf[n], qf[m][kk]);
    }
    __builtin_amdgcn_s_setprio(0);
    __syncthreads();                                         // K reads done (Ss aliases Ks)
    #pragma unroll
    for (int m = 0; m < 4; ++m) {
      int i = wr * 64 + m * 16 + (lane & 15);
      unsigned rowbase = (unsigned)i * 256;                  // byte offset of S row
      unsigned sw = (unsigned)(i & 15) << 4;
      #pragma unroll
      for (int n = 0; n < 4; ++n) {
        int j0 = wc * 64 + n * 16 + (lane >> 4) * 4;
        u16x4 pk;
        #pragma unroll
        for (int r = 0; r < 4; ++r) pk[r] = f2bf(fmaxf(sacc[n][m][r], 0.f));
        *(u16x4*)((char*)Ss + (rowbase + (((unsigned)j0 * 2) ^ sw))) = pk;
      }
    }
    __syncthreads();                                         // S visible
    __builtin_amdgcn_s_setprio(1);
    #pragma unroll
    for (int ks = 0; ks < 4; ++ks) {
      short8 sa[4], vb[2];
      #pragma unroll
      for (int m = 0; m < 4; ++m) {
        int i = wr * 64 + m * 16 + (lane & 15);
        unsigned c2 = (unsigned)(ks * 32 + (lane >> 4) * 8) * 2;
        sa[m] = *(const short8*)((const char*)Ss + (unsigned)i * 256 + (c2 ^ ((unsigned)(i & 15) << 4)));
      }
      #pragma unroll
      for (int n = 0; n < 2; ++n) {
        int r = wc * 32 + n * 16 + (lane & 15);
        int slot = ks * 4 + (lane >> 4);                     // 0..15
        vb[n] = *(const short8*)&Vs[r * 128 + ((slot ^ (r & 15)) * 8)];
      }
      #pragma unroll
      for (int m = 0; m < 4; ++m)
        #pragma unroll
        for (int n = 0; n < 2; ++n)
          MFMA_BF16(acc[m][n], sa[m], vb[n]);
    }
    __builtin_amdgcn_s_setprio(0);
  }
  #pragma unroll
  for (int m = 0; m < 4; ++m) {
    int row = wr * 64 + m * 16 + (lane >> 4) * 4;
    #pragma unroll
    for (int n = 0; n < 2; ++n) {
      int col = h * 64 + wc * 32 + n * 16 + (lane & 15);
      #pragma unroll
      for (int i = 0; i < 4; ++i)
        aout[(qrow0 + row + i) * 512 + col] = acc[m][n][i];
    }
  }
}

// ---------------- LayerNorm over 512, one wave per row, fp32 in -> bf16 out ----------------
__global__ __launch_bounds__(256) void ln_kernel(const float* __restrict__ x,
                                                 const float* __restrict__ g,
                                                 const float* __restrict__ bt,
                                                 u16* __restrict__ y) {
  const int lane = threadIdx.x & 63, wave = threadIdx.x >> 6;
  const size_t row = (size_t)blockIdx.x * 4 + wave;
  const float* xr = x + row * 512;
  f32x4 v0 = *(const f32x4*)&xr[lane * 4];
  f32x4 v1 = *(const f32x4*)&xr[256 + lane * 4];
  float s = v0[0] + v0[1] + v0[2] + v0[3] + v1[0] + v1[1] + v1[2] + v1[3];
  float q = v0[0]*v0[0] + v0[1]*v0[1] + v0[2]*v0[2] + v0[3]*v0[3]
          + v1[0]*v1[0] + v1[1]*v1[1] + v1[2]*v1[2] + v1[3]*v1[3];
  #pragma unroll
  for (int o = 32; o > 0; o >>= 1) { s += __shfl_xor(s, o); q += __shfl_xor(q, o); }
  float mean = s * (1.f / 512.f);
  float var  = q * (1.f / 512.f) - mean * mean;
  float rstd = rsqrtf(var + 1e-5f);
  f32x4 g0 = *(const f32x4*)&g[lane * 4],  g1 = *(const f32x4*)&g[256 + lane * 4];
  f32x4 b0 = *(const f32x4*)&bt[lane * 4], b1 = *(const f32x4*)&bt[256 + lane * 4];
  u16x4 o0, o1;
  #pragma unroll
  for (int i = 0; i < 4; ++i) {
    o0[i] = f2bf((v0[i] - mean) * rstd * g0[i] + b0[i]);
    o1[i] = f2bf((v1[i] - mean) * rstd * g1[i] + b1[i]);
  }
  *(u16x4*)&y[row * 512 + lane * 4] = o0;
  *(u16x4*)&y[row * 512 + 256 + lane * 4] = o1;
}

// ---------------- GEMM2: out = ln_bf16[16384,512] @ WoT[512,512]^T + bo (fp32 out) ----------------
// Grid: 1D 512, XCD-chunked decode (512 % 8 == 0).
__global__ __launch_bounds__(256) void gemm_out_kernel(const u16* __restrict__ A,
                                                       const u16* __restrict__ BT,
                                                       const float* __restrict__ bias,
                                                       float* __restrict__ out) {
  __shared__ u16 As[128 * 64];
  __shared__ u16 Bs[128 * 64];
  const int tid = threadIdx.x, lane = tid & 63, wave = tid >> 6;
  const int wr = wave >> 1, wc = wave & 1;
  const int bid = blockIdx.x;
  const int lin = (bid & 7) * 64 + (bid >> 3);
  const int m0 = (lin >> 2) * 128, n0 = (lin & 3) * 128;
  f32x4 acc[4][4] = {};
  for (int kt = 0; kt < 8; ++kt) {
    int k0 = kt * 64;
    __syncthreads();
    #pragma unroll
    for (int t = 0; t < 4; ++t) {
      int ch = wave * 4 + t;
      GLDS16(A + (size_t)(m0 + ch * 8 + (lane >> 3)) * 512 + k0 + (lane & 7) * 8, &As[ch * 512]);
      GLDS16(BT + (size_t)(n0 + ch * 8 + (lane >> 3)) * 512 + k0 + (lane & 7) * 8, &Bs[ch * 512]);
    }
    __syncthreads();
    #pragma unroll
    for (int kk = 0; kk < 2; ++kk) {
      short8 af[4], bfr[4];
      #pragma unroll
      for (int m = 0; m < 4; ++m)
        af[m] = *(const short8*)&As[(wr * 64 + m * 16 + (lane & 15)) * 64 + kk * 32 + (lane >> 4) * 8];
      #pragma unroll
      for (int n = 0; n < 4; ++n)
        bfr[n] = *(const short8*)&Bs[(wc * 64 + n * 16 + (lane & 15)) * 64 + kk * 32 + (lane >> 4) * 8];
      #pragma unroll
      for (int m = 0; m < 4; ++m)
        #pragma unroll
        for (int n = 0; n < 4; ++n)
          MFMA_BF16(acc[m][n], af[m], bfr[n]);
    }
  }
  const int row0 = m0 + wr * 64, col0 = n0 + wc * 64;
  #pragma unroll
  for (int m = 0; m < 4; ++m) {
    int row = row0 + m * 16 + (lane >> 4) * 4;
    #pragma unroll
    for (int n = 0; n < 4; ++n) {
      int col = col0 + n * 16 + (lane & 15);
      float bv = bias[col];
      #pragma unroll
      for (int i = 0; i < 4; ++i)
        out[(size_t)(row + i) * 512 + col] = acc[m][n][i] + bv;
    }
  }
}

extern "C" void kernel_launch(void* const* d_in, const int* in_sizes, int n_in,
                              void* d_out, int out_size, void* d_ws, size_t ws_size,
                              hipStream_t stream) {
  const float* x    = (const float*)d_in[0];
  const float* Wqkv = (const float*)d_in[1];
  const float* ln_g = (const float*)d_in[2];
  const float* ln_b = (const float*)d_in[3];
  const float* Wo   = (const float*)d_in[4];
  const float* bo   = (const float*)d_in[5];
  float* out = (float*)d_out;
  char* ws = (char*)d_ws;

  u16*   xbf   = (u16*)(ws);                               // 16 MB  [16384][512], reused for LN out
  u16*   wqkvt = (u16*)(ws + 16777216);                    // 1.5 MB [1536][512]
  u16*   wot   = (u16*)(ws + 18350080);                    // 0.5 MB [512][512]
  u16*   qkb   = (u16*)(ws + 18874368);                    // 32 MB  [16384][1024]
  u16*   vtb   = (u16*)(ws + 52428800);                    // 16 MB  [b*512+d][1024]
  float* att   = (float*)(ws + 69206016);                  // 32 MB  [16384][512]

  cvt_kernel<<<4096, 256, 0, stream>>>(x, xbf, 8388608 / 4);
  tcvt_kernel<<<dim3(24, 8), 256, 0, stream>>>(Wqkv, wqkvt, 512, 1536, 512);
  tcvt_kernel<<<dim3(8, 8), 256, 0, stream>>>(Wo, wot, 512, 512, 0);
  gemm_qkv_kernel<<<1536, 256, 0, stream>>>(xbf, wqkvt, qkb, vtb);
  attn_kernel<<<1024, 256, 0, stream>>>(qkb, vtb, att);
  ln_kernel<<<4096, 256, 0, stream>>>(att, ln_g, ln_b, xbf);
  gemm_out_kernel<<<512, 256, 0, stream>>>(xbf, wot, bo, out);
}